// Round 1
// baseline (177.139 us; speedup 1.0000x reference)
//
#include <hip/hip_runtime.h>
#include <stdint.h>
#include <math.h>

#define BB 8
#define NN 8192
#define DD 2048
#define NITERS 50

// Kernel 1: s[row] = dot(x[row,:], r[:]), row = b*NN+n. One wave (64 lanes) per row.
__global__ __launch_bounds__(256) void gemv_k(const float* __restrict__ x,
                                              const float* __restrict__ r,
                                              float* __restrict__ s) {
    __shared__ float rs[DD];
    for (int i = threadIdx.x; i < DD; i += 256) rs[i] = r[i];
    __syncthreads();
    const int wave = threadIdx.x >> 6;
    const int lane = threadIdx.x & 63;
    const int row = blockIdx.x * 4 + wave;
    const float* xr = x + (size_t)row * DD;
    float acc = 0.f;
#pragma unroll
    for (int j = 0; j < 8; ++j) {
        const int idx = (j * 64 + lane) * 4;
        const float4 v = *reinterpret_cast<const float4*>(xr + idx);
        const float4 w = *reinterpret_cast<const float4*>(rs + idx);
        acc = fmaf(v.x, w.x, acc);
        acc = fmaf(v.y, w.y, acc);
        acc = fmaf(v.z, w.z, acc);
        acc = fmaf(v.w, w.w, acc);
    }
#pragma unroll
    for (int off = 32; off > 0; off >>= 1) acc += __shfl_xor(acc, off, 64);
    if (lane == 0) s[row] = acc;
}

// Kernel 2: per batch row: 50-iter coordinate descent (scalar fixed point on a),
// then select top-ntok by (score desc, index asc) exploiting the score==1.0 tie group.
__global__ __launch_bounds__(1024) void router_k(const float* __restrict__ s_in,
                                                 const int* __restrict__ ntok_p,
                                                 float* __restrict__ out) {
    __shared__ uint64_t keys[NN];                            // 64 KiB total LDS
    float* srow = reinterpret_cast<float*>(keys);            // lower 32 KiB: s row
    float* fscr = reinterpret_cast<float*>(keys) + NN;       // upper 32 KiB: scratch
    int*   iscr = reinterpret_cast<int*>(fscr);

    const int row  = blockIdx.x;
    const int tid  = threadIdx.x;
    const int lane = tid & 63;
    const int wid  = tid >> 6;
    const int ntok = ntok_p[0];

    // coalesced load of this row's scores into LDS
    const float* sp = s_in + (size_t)row * NN;
    for (int i = tid; i < NN; i += 1024) srow[i] = sp[i];
    __syncthreads();

    // each thread owns 8 contiguous elements (stable index order for compaction)
    float sv[8];
#pragma unroll
    for (int j = 0; j < 8; ++j) sv[j] = srow[tid * 8 + j];

    const float logk = logf(fminf((float)ntok * 1.125f, (float)NN));
    // iteration 1: b0=-s => sb=0 exactly => lse = log(NN)
    float a = logk - logf((float)NN);

    // iterations 2..NITERS: a = logk - logsumexp(s + b), b = -relu(s + a)
    for (int it = 1; it < NITERS; ++it) {
        float sb[8];
        float lmax = -INFINITY;
#pragma unroll
        for (int j = 0; j < 8; ++j) {
            const float t = sv[j] + a;       // mirrors reference op order exactly
            const float b = -fmaxf(t, 0.f);
            sb[j] = sv[j] + b;
            lmax = fmaxf(lmax, sb[j]);
        }
#pragma unroll
        for (int off = 32; off > 0; off >>= 1) lmax = fmaxf(lmax, __shfl_xor(lmax, off, 64));
        if (lane == 0) fscr[wid] = lmax;
        __syncthreads();
        if (tid == 0) {
            float m = fscr[0];
            for (int i = 1; i < 16; ++i) m = fmaxf(m, fscr[i]);
            fscr[16] = m;
        }
        __syncthreads();
        const float M = fscr[16];
        __syncthreads();
        float lsum = 0.f;
#pragma unroll
        for (int j = 0; j < 8; ++j) lsum += expf(sb[j] - M);
#pragma unroll
        for (int off = 32; off > 0; off >>= 1) lsum += __shfl_xor(lsum, off, 64);
        if (lane == 0) fscr[wid] = lsum;
        __syncthreads();
        if (tid == 0) {
            float ssum = 0.f;
            for (int i = 0; i < 16; ++i) ssum += fscr[i];
            fscr[16] = ssum;
        }
        __syncthreads();
        const float S = fscr[16];
        __syncthreads();
        a = logk - (logf(S) + M);
    }

    // final scores: exp((s + a + b)) with b = -relu(s+a)  ==> exp(min(s+a,0))
    int flags = 0, cnt = 0;
#pragma unroll
    for (int j = 0; j < 8; ++j) {
        const float t = sv[j] + a;
        const float b = -fmaxf(t, 0.f);
        const float e = expf(t + b);         // t+b == min(t,0) exactly in f32
        if (e == 1.0f) { flags |= (1 << j); ++cnt; }
    }

    // block-wide exclusive scan of per-thread tie counts
    int x = cnt;
#pragma unroll
    for (int off = 1; off < 64; off <<= 1) {
        const int y = __shfl_up(x, off, 64);
        if (lane >= off) x += y;
    }
    if (lane == 63) iscr[wid] = x;
    __syncthreads();
    if (tid == 0) {
        int run = 0;
        for (int i = 0; i < 16; ++i) { const int t = iscr[i]; iscr[i] = run; run += t; }
        iscr[16] = run;
    }
    __syncthreads();
    const int base  = iscr[wid] + (x - cnt);
    const int total = iscr[16];
    __syncthreads();

    float* out1 = out + (size_t)gridDim.x * ntok;

    // output 0: straight-through => exactly 1.0 everywhere
    for (int q = tid; q < ntok; q += 1024) out[(size_t)row * ntok + q] = 1.0f;

    if (total >= ntok) {
        // common path: top-ntok are all ties at 1.0 -> lowest ntok indices, ascending
        int p = base;
#pragma unroll
        for (int j = 0; j < 8; ++j) {
            if (flags & (1 << j)) {
                if (p < ntok) out1[(size_t)row * ntok + p] = (float)(tid * 8 + j);
                ++p;
            }
        }
    } else {
        // fallback (not expected): exact stable top-k via bitonic sort of
        // key = (score_bits desc, index asc)
        uint64_t myk[8];
#pragma unroll
        for (int j = 0; j < 8; ++j) {
            const float t = sv[j] + a;
            const float b = -fmaxf(t, 0.f);
            const float e = expf(t + b);     // e > 0, so float bits are order-preserving
            const uint32_t bits = __float_as_uint(e);
            myk[j] = ((uint64_t)bits << 32) | (uint32_t)(0xFFFFFFFFu - (uint32_t)(tid * 8 + j));
        }
        __syncthreads();
#pragma unroll
        for (int j = 0; j < 8; ++j) keys[tid * 8 + j] = myk[j];
        __syncthreads();
        for (unsigned k = 2; k <= NN; k <<= 1) {
            for (unsigned jj = k >> 1; jj > 0; jj >>= 1) {
                for (unsigned p = tid; p < NN / 2; p += 1024) {
                    const unsigned i   = ((p & ~(jj - 1)) << 1) | (p & (jj - 1));
                    const unsigned ixj = i | jj;
                    const bool up = ((i & k) == 0);
                    const uint64_t ka = keys[i], kb = keys[ixj];
                    if ((ka < kb) == up) { keys[i] = kb; keys[ixj] = ka; }  // descending overall
                }
                __syncthreads();
            }
        }
        for (int p = tid; p < ntok; p += 1024) {
            const uint32_t idx = 0xFFFFFFFFu - (uint32_t)(keys[p] & 0xFFFFFFFFull);
            out1[(size_t)row * ntok + p] = (float)idx;
        }
    }
}

extern "C" void kernel_launch(void* const* d_in, const int* in_sizes, int n_in,
                              void* d_out, int out_size, void* d_ws, size_t ws_size,
                              hipStream_t stream) {
    const float* x = (const float*)d_in[0];   // [8, 8192, 2048] f32
    const float* r = (const float*)d_in[1];   // [1, 2048] f32
    const int* ntok = (const int*)d_in[2];    // scalar int
    float* out = (float*)d_out;               // [8*ntok] scores(=1.0) then [8*ntok] indices (as float)
    float* s = (float*)d_ws;                  // [8*8192] f32 routing scores

    gemv_k<<<(BB * NN) / 4, 256, 0, stream>>>(x, r, s);
    router_k<<<BB, 1024, 0, stream>>>(s, ntok, out);
}

// Round 3
// 155.665 us; speedup vs baseline: 1.1380x; 1.1380x over previous
//
#include <hip/hip_runtime.h>
#include <stdint.h>
#include <math.h>

#define BB 8
#define NN 8192
#define DD 2048
#define NITERS 50

typedef float f32x4 __attribute__((ext_vector_type(4)));

// Kernel 1: s[row] = dot(x[row,:], r[:]). One wave per 2 rows, 4 waves/block.
__global__ __launch_bounds__(256) void gemv_k(const float* __restrict__ x,
                                              const float* __restrict__ r,
                                              float* __restrict__ s) {
    __shared__ float rs[DD];
#pragma unroll
    for (int i = 0; i < 8; ++i) rs[threadIdx.x + i * 256] = r[threadIdx.x + i * 256];
    __syncthreads();
    const int wave = threadIdx.x >> 6;
    const int lane = threadIdx.x & 63;
    const int row = blockIdx.x * 8 + wave * 2;
    const float* x0 = x + (size_t)row * DD;

    f32x4 w[8];
#pragma unroll
    for (int j = 0; j < 8; ++j) w[j] = *reinterpret_cast<const f32x4*>(rs + (j * 64 + lane) * 4);

    float a0 = 0.f, a1 = 0.f;
#pragma unroll
    for (int j = 0; j < 8; ++j) {
        const int idx = (j * 64 + lane) * 4;
        const f32x4 v0 = __builtin_nontemporal_load(reinterpret_cast<const f32x4*>(x0 + idx));
        const f32x4 v1 = __builtin_nontemporal_load(reinterpret_cast<const f32x4*>(x0 + DD + idx));
        a0 = fmaf(v0.x, w[j].x, a0); a0 = fmaf(v0.y, w[j].y, a0);
        a0 = fmaf(v0.z, w[j].z, a0); a0 = fmaf(v0.w, w[j].w, a0);
        a1 = fmaf(v1.x, w[j].x, a1); a1 = fmaf(v1.y, w[j].y, a1);
        a1 = fmaf(v1.z, w[j].z, a1); a1 = fmaf(v1.w, w[j].w, a1);
    }
#pragma unroll
    for (int off = 32; off > 0; off >>= 1) {
        a0 += __shfl_xor(a0, off, 64);
        a1 += __shfl_xor(a1, off, 64);
    }
    if (lane == 0) { s[row] = a0; s[row + 1] = a1; }
}

// Kernel 2: per batch row: 50-iter coordinate descent (scalar fixed point on a),
// then select top-ntok by (score desc, index asc) exploiting the score==1.0 tie group.
__global__ __launch_bounds__(1024) void router_k(const float* __restrict__ s_in,
                                                 const int* __restrict__ ntok_p,
                                                 float* __restrict__ out) {
    __shared__ uint64_t keys[NN];                            // 64 KiB total LDS
    float* srow = reinterpret_cast<float*>(keys);            // lower 32 KiB: s row
    float* fscr = reinterpret_cast<float*>(keys) + NN;       // upper 32 KiB: scratch
    int*   iscr = reinterpret_cast<int*>(fscr);

    const int row  = blockIdx.x;
    const int tid  = threadIdx.x;
    const int lane = tid & 63;
    const int wid  = tid >> 6;
    const int ntok = ntok_p[0];

    const float* sp = s_in + (size_t)row * NN;
    for (int i = tid; i < NN; i += 1024) srow[i] = sp[i];
    __syncthreads();

    // each thread owns 8 contiguous elements (stable index order for compaction)
    float sv[8];
#pragma unroll
    for (int j = 0; j < 8; ++j) sv[j] = srow[tid * 8 + j];

    // row max, computed once (max of sb_i = s_i - relu(s_i+a) is exactly min(maxs,-a))
    float mx = sv[0];
#pragma unroll
    for (int j = 1; j < 8; ++j) mx = fmaxf(mx, sv[j]);
#pragma unroll
    for (int off = 32; off > 0; off >>= 1) mx = fmaxf(mx, __shfl_xor(mx, off, 64));
    if (lane == 0) fscr[wid] = mx;
    __syncthreads();
    if (wid == 0) {
        float v = (lane < 16) ? fscr[lane] : -INFINITY;
#pragma unroll
        for (int off = 8; off > 0; off >>= 1) v = fmaxf(v, __shfl_xor(v, off, 64));
        if (lane == 0) fscr[16] = v;
    }
    __syncthreads();
    const float maxs = fscr[16];

    const float logk = logf(fminf((float)ntok * 1.125f, (float)NN));
    // iteration 1: b0=-s => sb=0 exactly => lse = log(NN)
    float a = logk - logf((float)NN);

    // iterations 2..NITERS: a = logk - logsumexp(s + b), b = -relu(s + a)
    for (int it = 1; it < NITERS; ++it) {
        const float M = fminf(maxs, -a);
        float sum = 0.f;
#pragma unroll
        for (int j = 0; j < 8; ++j) {
            const float t  = sv[j] + a;              // mirrors reference op order
            const float sb = sv[j] - fmaxf(t, 0.f);  // s + (-relu(s+a))
            sum += expf(sb - M);
        }
#pragma unroll
        for (int off = 32; off > 0; off >>= 1) sum += __shfl_xor(sum, off, 64);
        if (lane == 0) fscr[wid] = sum;
        __syncthreads();
        if (wid == 0) {
            float v = (lane < 16) ? fscr[lane] : 0.f;
#pragma unroll
            for (int off = 8; off > 0; off >>= 1) v += __shfl_xor(v, off, 64);
            if (lane == 0) fscr[16] = logk - (logf(v) + M);
        }
        __syncthreads();
        a = fscr[16];
    }

    // final scores: exp(s + a + b) with b = -relu(s+a)  ==> 1.0 exactly iff s+a >= 0
    int flags = 0, cnt = 0;
#pragma unroll
    for (int j = 0; j < 8; ++j) {
        const float t = sv[j] + a;
        const float b = -fmaxf(t, 0.f);
        const float e = expf(t + b);
        if (e == 1.0f) { flags |= (1 << j); ++cnt; }
    }

    // block-wide exclusive scan of per-thread tie counts
    int x = cnt;
#pragma unroll
    for (int off = 1; off < 64; off <<= 1) {
        const int y = __shfl_up(x, off, 64);
        if (lane >= off) x += y;
    }
    __syncthreads();   // srow/fscr reuse barrier (sv already in regs)
    if (lane == 63) iscr[wid] = x;
    __syncthreads();
    if (tid == 0) {
        int run = 0;
        for (int i = 0; i < 16; ++i) { const int t = iscr[i]; iscr[i] = run; run += t; }
        iscr[16] = run;
    }
    __syncthreads();
    const int base  = iscr[wid] + (x - cnt);
    const int total = iscr[16];
    __syncthreads();

    float* out1 = out + (size_t)gridDim.x * ntok;

    // output 0: straight-through => exactly 1.0 everywhere
    for (int q = tid; q < ntok; q += 1024) out[(size_t)row * ntok + q] = 1.0f;

    if (total >= ntok) {
        // common path: top-ntok are all ties at 1.0 -> lowest ntok indices, ascending
        int p = base;
#pragma unroll
        for (int j = 0; j < 8; ++j) {
            if (flags & (1 << j)) {
                if (p < ntok) out1[(size_t)row * ntok + p] = (float)(tid * 8 + j);
                ++p;
            }
        }
    } else {
        // fallback (not expected): exact stable top-k via bitonic sort of
        // key = (score_bits desc, index asc)
        uint64_t myk[8];
#pragma unroll
        for (int j = 0; j < 8; ++j) {
            const float t = sv[j] + a;
            const float b = -fmaxf(t, 0.f);
            const float e = expf(t + b);     // e > 0, so float bits are order-preserving
            const uint32_t bits = __float_as_uint(e);
            myk[j] = ((uint64_t)bits << 32) | (uint32_t)(0xFFFFFFFFu - (uint32_t)(tid * 8 + j));
        }
        __syncthreads();
#pragma unroll
        for (int j = 0; j < 8; ++j) keys[tid * 8 + j] = myk[j];
        __syncthreads();
        for (unsigned k = 2; k <= NN; k <<= 1) {
            for (unsigned jj = k >> 1; jj > 0; jj >>= 1) {
                for (unsigned p = tid; p < NN / 2; p += 1024) {
                    const unsigned i   = ((p & ~(jj - 1)) << 1) | (p & (jj - 1));
                    const unsigned ixj = i | jj;
                    const bool up = ((i & k) == 0);
                    const uint64_t ka = keys[i], kb = keys[ixj];
                    if ((ka < kb) == up) { keys[i] = kb; keys[ixj] = ka; }  // descending overall
                }
                __syncthreads();
            }
        }
        for (int p = tid; p < ntok; p += 1024) {
            const uint32_t idx = 0xFFFFFFFFu - (uint32_t)(keys[p] & 0xFFFFFFFFull);
            out1[(size_t)row * ntok + p] = (float)idx;
        }
    }
}

extern "C" void kernel_launch(void* const* d_in, const int* in_sizes, int n_in,
                              void* d_out, int out_size, void* d_ws, size_t ws_size,
                              hipStream_t stream) {
    const float* x = (const float*)d_in[0];   // [8, 8192, 2048] f32
    const float* r = (const float*)d_in[1];   // [1, 2048] f32
    const int* ntok = (const int*)d_in[2];    // scalar int
    float* out = (float*)d_out;               // [8*ntok] scores(=1.0) then [8*ntok] indices (as float)
    float* s = (float*)d_ws;                  // [8*8192] f32 routing scores

    gemv_k<<<(BB * NN) / 8, 256, 0, stream>>>(x, r, s);
    router_k<<<BB, 1024, 0, stream>>>(s, ntok, out);
}

// Round 4
// 153.094 us; speedup vs baseline: 1.1571x; 1.0168x over previous
//
#include <hip/hip_runtime.h>
#include <stdint.h>
#include <math.h>

#define BB 8
#define NN 8192
#define DD 2048
#define NITERS 50

typedef float f32x4 __attribute__((ext_vector_type(4)));

// Kernel 1: s[row] = dot(x[row,:], r[:]). One wave per 2 rows, 4 waves/block.
// r read directly from global (L1-resident, 8 KiB); no LDS, no barrier.
__global__ __launch_bounds__(256) void gemv_k(const float* __restrict__ x,
                                              const float* __restrict__ r,
                                              float* __restrict__ s) {
    const int wave = threadIdx.x >> 6;
    const int lane = threadIdx.x & 63;
    const int row = blockIdx.x * 8 + wave * 2;
    const float* x0 = x + (size_t)row * DD;

    f32x4 w[8];
#pragma unroll
    for (int j = 0; j < 8; ++j) w[j] = *reinterpret_cast<const f32x4*>(r + (j * 64 + lane) * 4);

    float a0 = 0.f, a1 = 0.f;
#pragma unroll
    for (int j = 0; j < 8; ++j) {
        const int idx = (j * 64 + lane) * 4;
        const f32x4 v0 = *reinterpret_cast<const f32x4*>(x0 + idx);
        const f32x4 v1 = *reinterpret_cast<const f32x4*>(x0 + DD + idx);
        a0 = fmaf(v0.x, w[j].x, a0); a0 = fmaf(v0.y, w[j].y, a0);
        a0 = fmaf(v0.z, w[j].z, a0); a0 = fmaf(v0.w, w[j].w, a0);
        a1 = fmaf(v1.x, w[j].x, a1); a1 = fmaf(v1.y, w[j].y, a1);
        a1 = fmaf(v1.z, w[j].z, a1); a1 = fmaf(v1.w, w[j].w, a1);
    }
#pragma unroll
    for (int off = 32; off > 0; off >>= 1) {
        a0 += __shfl_xor(a0, off, 64);
        a1 += __shfl_xor(a1, off, 64);
    }
    if (lane == 0) { s[row] = a0; s[row + 1] = a1; }
}

// Kernel 2: per batch row: 50-iter coordinate descent (scalar fixed point on a),
// then select top-ntok by (score desc, index asc) exploiting the score==1.0 tie group.
// Identity used: for this problem max(s+b) == -a every iteration, so the reference's
// logsumexp equals log(U) - a with U = sum_i exp(min(s_i + a, 0)); terms <= 1.
__global__ __launch_bounds__(1024) void router_k(const float* __restrict__ s_in,
                                                 const int* __restrict__ ntok_p,
                                                 float* __restrict__ out) {
    __shared__ uint64_t keys[NN];                            // 64 KiB total LDS
    float* srow = reinterpret_cast<float*>(keys);            // lower 32 KiB: s row
    float* fscr = reinterpret_cast<float*>(keys) + NN;       // upper 32 KiB: scratch
    // fscr[0..15]  : partials, even iters
    // fscr[16..31] : partials, odd iters
    int* iscr = reinterpret_cast<int*>(fscr + 64);           // scan scratch (disjoint)

    const int row  = blockIdx.x;
    const int tid  = threadIdx.x;
    const int lane = tid & 63;
    const int wid  = tid >> 6;
    const int ntok = ntok_p[0];

    const float* sp = s_in + (size_t)row * NN;
    for (int i = tid; i < NN; i += 1024) srow[i] = sp[i];
    __syncthreads();

    // each thread owns 8 contiguous elements (stable index order for compaction)
    float sv[8];
#pragma unroll
    for (int j = 0; j < 8; ++j) sv[j] = srow[tid * 8 + j];

    const float logk = logf(fminf((float)ntok * 1.125f, (float)NN));
    // iteration 1: b0=-s => sb=0 exactly => lse = log(NN)
    float a = logk - logf((float)NN);

    // iterations 2..NITERS: a = logk - log(U) + a, U = sum exp(min(s+a,0))
    for (int it = 1; it < NITERS; ++it) {
        float u = 0.f;
#pragma unroll
        for (int j = 0; j < 8; ++j) u += expf(fminf(sv[j] + a, 0.f));
#pragma unroll
        for (int off = 32; off > 0; off >>= 1) u += __shfl_xor(u, off, 64);
        float* buf = fscr + (it & 1) * 16;
        if (lane == 0) buf[wid] = u;
        __syncthreads();
        float U = buf[0];
#pragma unroll
        for (int i = 1; i < 16; ++i) U += buf[i];   // broadcast reads; identical in all threads
        a = (logk - logf(U)) + a;
    }

    // final scores: exp(min(s+a,0)) == 1.0f is exactly the reference tie predicate
    int flags = 0, cnt = 0;
#pragma unroll
    for (int j = 0; j < 8; ++j) {
        const float e = expf(fminf(sv[j] + a, 0.f));
        if (e == 1.0f) { flags |= (1 << j); ++cnt; }
    }

    // block-wide exclusive scan of per-thread tie counts
    int x = cnt;
#pragma unroll
    for (int off = 1; off < 64; off <<= 1) {
        const int y = __shfl_up(x, off, 64);
        if (lane >= off) x += y;
    }
    if (lane == 63) iscr[wid] = x;
    __syncthreads();
    if (tid == 0) {
        int run = 0;
        for (int i = 0; i < 16; ++i) { const int t = iscr[i]; iscr[i] = run; run += t; }
        iscr[16] = run;
    }
    __syncthreads();
    const int base  = iscr[wid] + (x - cnt);
    const int total = iscr[16];

    float* out1 = out + (size_t)gridDim.x * ntok;

    // output 0: straight-through => exactly 1.0 everywhere
    for (int q = tid; q < ntok; q += 1024) out[(size_t)row * ntok + q] = 1.0f;

    if (total >= ntok) {
        // common path: top-ntok are all ties at 1.0 -> lowest ntok indices, ascending
        int p = base;
#pragma unroll
        for (int j = 0; j < 8; ++j) {
            if (flags & (1 << j)) {
                if (p < ntok) out1[(size_t)row * ntok + p] = (float)(tid * 8 + j);
                ++p;
            }
        }
    } else {
        // fallback (not expected): exact stable top-k via bitonic sort of
        // key = (score_bits desc, index asc)
        uint64_t myk[8];
#pragma unroll
        for (int j = 0; j < 8; ++j) {
            const float e = expf(fminf(sv[j] + a, 0.f));   // e > 0: float bits order-preserving
            const uint32_t bits = __float_as_uint(e);
            myk[j] = ((uint64_t)bits << 32) | (uint32_t)(0xFFFFFFFFu - (uint32_t)(tid * 8 + j));
        }
        __syncthreads();
#pragma unroll
        for (int j = 0; j < 8; ++j) keys[tid * 8 + j] = myk[j];
        __syncthreads();
        for (unsigned k = 2; k <= NN; k <<= 1) {
            for (unsigned jj = k >> 1; jj > 0; jj >>= 1) {
                for (unsigned p = tid; p < NN / 2; p += 1024) {
                    const unsigned i   = ((p & ~(jj - 1)) << 1) | (p & (jj - 1));
                    const unsigned ixj = i | jj;
                    const bool up = ((i & k) == 0);
                    const uint64_t ka = keys[i], kb = keys[ixj];
                    if ((ka < kb) == up) { keys[i] = kb; keys[ixj] = ka; }  // descending overall
                }
                __syncthreads();
            }
        }
        for (int p = tid; p < ntok; p += 1024) {
            const uint32_t idx = 0xFFFFFFFFu - (uint32_t)(keys[p] & 0xFFFFFFFFull);
            out1[(size_t)row * ntok + p] = (float)idx;
        }
    }
}

extern "C" void kernel_launch(void* const* d_in, const int* in_sizes, int n_in,
                              void* d_out, int out_size, void* d_ws, size_t ws_size,
                              hipStream_t stream) {
    const float* x = (const float*)d_in[0];   // [8, 8192, 2048] f32
    const float* r = (const float*)d_in[1];   // [1, 2048] f32
    const int* ntok = (const int*)d_in[2];    // scalar int
    float* out = (float*)d_out;               // [8*ntok] scores(=1.0) then [8*ntok] indices (as float)
    float* s = (float*)d_ws;                  // [8*8192] f32 routing scores

    gemv_k<<<(BB * NN) / 8, 256, 0, stream>>>(x, r, s);
    router_k<<<BB, 1024, 0, stream>>>(s, ntok, out);
}

// Round 5
// 126.648 us; speedup vs baseline: 1.3987x; 1.2088x over previous
//
#include <hip/hip_runtime.h>
#include <stdint.h>
#include <math.h>

#define BB 8
#define NN 8192
#define DD 2048
#define NITERS 50
#define NTHR 512            // router threads: 8 waves
#define EPT  16             // elements per router thread (NN/NTHR)

typedef float f32x4 __attribute__((ext_vector_type(4)));

// Kernel 1 (UNCHANGED from round 4): s[row] = dot(x[row,:], r[:]).
__global__ __launch_bounds__(256) void gemv_k(const float* __restrict__ x,
                                              const float* __restrict__ r,
                                              float* __restrict__ s) {
    const int wave = threadIdx.x >> 6;
    const int lane = threadIdx.x & 63;
    const int row = blockIdx.x * 8 + wave * 2;
    const float* x0 = x + (size_t)row * DD;

    f32x4 w[8];
#pragma unroll
    for (int j = 0; j < 8; ++j) w[j] = *reinterpret_cast<const f32x4*>(r + (j * 64 + lane) * 4);

    float a0 = 0.f, a1 = 0.f;
#pragma unroll
    for (int j = 0; j < 8; ++j) {
        const int idx = (j * 64 + lane) * 4;
        const f32x4 v0 = *reinterpret_cast<const f32x4*>(x0 + idx);
        const f32x4 v1 = *reinterpret_cast<const f32x4*>(x0 + DD + idx);
        a0 = fmaf(v0.x, w[j].x, a0); a0 = fmaf(v0.y, w[j].y, a0);
        a0 = fmaf(v0.z, w[j].z, a0); a0 = fmaf(v0.w, w[j].w, a0);
        a1 = fmaf(v1.x, w[j].x, a1); a1 = fmaf(v1.y, w[j].y, a1);
        a1 = fmaf(v1.z, w[j].z, a1); a1 = fmaf(v1.w, w[j].w, a1);
    }
#pragma unroll
    for (int off = 32; off > 0; off >>= 1) {
        a0 += __shfl_xor(a0, off, 64);
        a1 += __shfl_xor(a1, off, 64);
    }
    if (lane == 0) { s[row] = a0; s[row + 1] = a1; }
}

// Kernel 2: 512 threads/row, 16 elems/thread in registers, latency-tuned iteration.
// Identity: reference lse == log(U) - a with U = sum_i exp(min(s_i + a, 0)).
__global__ __launch_bounds__(NTHR) void router_k(const float* __restrict__ s_in,
                                                 const int* __restrict__ ntok_p,
                                                 float* __restrict__ out) {
    __shared__ uint64_t keys[NN];          // 64 KiB (fallback sort only)
    __shared__ float fscr[2][8];           // ping-pong wave partials
    __shared__ int   iscr[8 + 1];          // scan scratch

    const int row  = blockIdx.x;
    const int tid  = threadIdx.x;
    const int lane = tid & 63;
    const int wid  = tid >> 6;
    const int ntok = ntok_p[0];

    // direct global->register load, 4 x f32x4 per thread (blocked ownership: [tid*16, tid*16+16))
    const float* sp = s_in + (size_t)row * NN;
    f32x4 sv4[4];
#pragma unroll
    for (int c = 0; c < 4; ++c) sv4[c] = *reinterpret_cast<const f32x4*>(sp + tid * EPT + c * 4);
    float sv[EPT];
#pragma unroll
    for (int c = 0; c < 4; ++c) {
        sv[c * 4 + 0] = sv4[c].x; sv[c * 4 + 1] = sv4[c].y;
        sv[c * 4 + 2] = sv4[c].z; sv[c * 4 + 3] = sv4[c].w;
    }

    const float logk = logf(fminf((float)ntok * 1.125f, (float)NN));
    float a = logk - logf((float)NN);   // iteration 1 closed form

    for (int it = 1; it < NITERS; ++it) {
        // per-thread tree sum of exp(min(s+a,0)) over 16 elems
        float e[EPT];
#pragma unroll
        for (int j = 0; j < EPT; ++j) e[j] = __expf(fminf(sv[j] + a, 0.f));
#pragma unroll
        for (int st = 1; st < EPT; st <<= 1)
#pragma unroll
            for (int j = 0; j < EPT; j += 2 * st) e[j] += e[j + st];
        float u = e[0];
#pragma unroll
        for (int off = 32; off > 0; off >>= 1) u += __shfl_xor(u, off, 64);
        float* buf = fscr[it & 1];
        if (lane == 0) buf[wid] = u;
        __syncthreads();
        // two vector reads + 7-add tree (no serial scalar LDS chain)
        const f32x4 p0 = *reinterpret_cast<const f32x4*>(&buf[0]);
        const f32x4 p1 = *reinterpret_cast<const f32x4*>(&buf[4]);
        const float U = ((p0.x + p0.y) + (p0.z + p0.w)) + ((p1.x + p1.y) + (p1.z + p1.w));
        a = (logk - __logf(U)) + a;
    }

    // membership: exp(min(s+a,0)) == 1.0f  (exact reference tie predicate)
    int flags = 0, cnt = 0;
#pragma unroll
    for (int j = 0; j < EPT; ++j) {
        const float e2 = __expf(fminf(sv[j] + a, 0.f));
        if (e2 == 1.0f) { flags |= (1 << j); ++cnt; }
    }

    // block-wide exclusive scan of per-thread member counts
    int x = cnt;
#pragma unroll
    for (int off = 1; off < 64; off <<= 1) {
        const int y = __shfl_up(x, off, 64);
        if (lane >= off) x += y;
    }
    if (lane == 63) iscr[wid] = x;
    __syncthreads();
    // redundant per-thread prefix over the 8 wave totals
    int wbase = 0, total = 0;
#pragma unroll
    for (int w2 = 0; w2 < 8; ++w2) {
        const int t = iscr[w2];
        if (w2 < wid) wbase += t;
        total += t;
    }
    const int base = wbase + (x - cnt);

    float* out1 = out + (size_t)gridDim.x * ntok;

    // output 0: straight-through => exactly 1.0 everywhere
    for (int q = tid; q < ntok; q += NTHR) out[(size_t)row * ntok + q] = 1.0f;

    if (total >= ntok) {
        // top-ntok are all ties at 1.0 -> lowest ntok member indices, ascending
        int p = base;
#pragma unroll
        for (int j = 0; j < EPT; ++j) {
            if (flags & (1 << j)) {
                if (p < ntok) out1[(size_t)row * ntok + p] = (float)(tid * EPT + j);
                ++p;
            }
        }
    } else {
        // fallback (not expected): exact stable top-k via bitonic sort,
        // key = (score_bits desc, index asc)
        __syncthreads();
#pragma unroll
        for (int j = 0; j < EPT; ++j) {
            const float e2 = __expf(fminf(sv[j] + a, 0.f));
            const uint32_t bits = __float_as_uint(e2);
            keys[tid * EPT + j] =
                ((uint64_t)bits << 32) | (uint32_t)(0xFFFFFFFFu - (uint32_t)(tid * EPT + j));
        }
        __syncthreads();
        for (unsigned k = 2; k <= NN; k <<= 1) {
            for (unsigned jj = k >> 1; jj > 0; jj >>= 1) {
                for (unsigned p = tid; p < NN / 2; p += NTHR) {
                    const unsigned i   = ((p & ~(jj - 1)) << 1) | (p & (jj - 1));
                    const unsigned ixj = i | jj;
                    const bool up = ((i & k) == 0);
                    const uint64_t ka = keys[i], kb = keys[ixj];
                    if ((ka < kb) == up) { keys[i] = kb; keys[ixj] = ka; }
                }
                __syncthreads();
            }
        }
        for (int p = tid; p < ntok; p += NTHR) {
            const uint32_t idx = 0xFFFFFFFFu - (uint32_t)(keys[p] & 0xFFFFFFFFull);
            out1[(size_t)row * ntok + p] = (float)idx;
        }
    }
}

extern "C" void kernel_launch(void* const* d_in, const int* in_sizes, int n_in,
                              void* d_out, int out_size, void* d_ws, size_t ws_size,
                              hipStream_t stream) {
    const float* x = (const float*)d_in[0];   // [8, 8192, 2048] f32
    const float* r = (const float*)d_in[1];   // [1, 2048] f32
    const int* ntok = (const int*)d_in[2];    // scalar int
    float* out = (float*)d_out;               // [8*ntok] scores(=1.0) then [8*ntok] indices (as float)
    float* s = (float*)d_ws;                  // [8*8192] f32 routing scores

    gemv_k<<<(BB * NN) / 8, 256, 0, stream>>>(x, r, s);
    router_k<<<BB, NTHR, 0, stream>>>(s, ntok, out);
}